// Round 9
// baseline (115.026 us; speedup 1.0000x reference)
//
#include <hip/hip_runtime.h>
#include <math.h>

#define NH   32
#define NKVH 8
#define HD   64
#define WIN  256
#define BB   2
#define SS   2048

typedef short short8 __attribute__((ext_vector_type(8)));
typedef float f32x4  __attribute__((ext_vector_type(4)));

__device__ __forceinline__ ushort f2bf(float x) {
    union { float f; unsigned u; } v; v.f = x;
    unsigned u = v.u + 0x7FFF + ((v.u >> 16) & 1);   // RNE
    return (ushort)(u >> 16);
}

__device__ __forceinline__ int cvtpk_bf16(float lo, float hi) {
    int r;
    asm("v_cvt_pk_bf16_f32 %0, %1, %2" : "=v"(r) : "v"(lo), "v"(hi));
    return r;
}

// XOR-swizzle within a 4KB chunk (bits 4-6 ^= bits 7-9). Applied at prep-store
// AND lds-read; global_load_lds stages linearly so LDS holds the same image.
__device__ __forceinline__ int swz(int L) { return L ^ (((L >> 7) & 7) << 4); }

__device__ __forceinline__ void stage16(const void* g, void* l) {
    __builtin_amdgcn_global_load_lds(
        (const __attribute__((address_space(1))) unsigned int*)g,
        (__attribute__((address_space(3))) unsigned int*)l, 16, 0, 0);
}

// ---- fused pre-pass (unchanged from R8): swizzled 4KB chunk images via LDS,
// coalesced copy-out. Kr chunk: [key%32][d] bf16 rows of 128B, XOR-swizzled.
// Vt chunk: [d][slot] bf16 rows of 64B, XOR-swizzled, slot holds key
// sigma(slot) = (slot>>3)*4 + (slot&3) + ((slot>>2)&1)*16  (QK^T C-layout ==
// PV A-frag layout => no cross-lane exchange in the main kernel).
__global__ __launch_bounds__(256) void prep_kv(const float* __restrict__ K,
                                               const float* __restrict__ V,
                                               ushort* __restrict__ Kr,
                                               ushort* __restrict__ Vt) {
    __shared__ __align__(16) ushort ldsK[2048];
    __shared__ __align__(16) ushort ldsV[2048];
    const int bidx = blockIdx.x;                // (b, kvh, sblk): 2*8*64
    const int sblk = bidx & 63;
    const int s0   = sblk * 32;
    const int kvh  = (bidx >> 6) & 7;
    const int b    = bidx >> 9;
    const int tid  = threadIdx.x;

    {
        const int key = tid >> 3, dg = tid & 7;
        const int s   = s0 + key;
        const float* krow = K + (size_t)(b * SS + s) * (NKVH * HD) + kvh * HD + dg * 8;
        float x[8];
        *(float4*)(x)     = *(const float4*)(krow);
        *(float4*)(x + 4) = *(const float4*)(krow + 4);
        float inv = __powf(10000.f, -(float)((dg & 3) * 8) * (1.f / 32.f));
        const float ratio = 0.74989420933f;      // 10000^(-1/32)
        ushort out[8];
#pragma unroll
        for (int j = 0; j < 8; ++j) {
            float partner = __shfl(x[j], (tid & 63) ^ 4, 64);   // d ^ 32 holder
            float sn, cs;
            __sincosf((float)s * inv, &sn, &cs);
            out[j] = f2bf(x[j] * cs + ((dg < 4) ? -partner : partner) * sn);
            inv *= ratio;
        }
        *(short8*)((char*)ldsK + swz(key * 128 + dg * 16)) = *(short8*)out;
    }
    {
        const int kp = tid & 15, dq = tid >> 4;
        const int c  = 2 * kp;
        const int kf = ((c >> 3) * 4) + (c & 3) + (((c >> 2) & 1) * 16);
        const float* v0 = V + (size_t)(b * SS + s0 + kf) * (NKVH * HD) + kvh * HD + dq * 4;
        float4 a = *(const float4*)v0;
        float4 cvec = *(const float4*)(v0 + NKVH * HD);   // key kf+1
#pragma unroll
        for (int j = 0; j < 4; ++j) {
            int d = dq * 4 + j;
            unsigned w = (unsigned)f2bf(((const float*)&a)[j])
                       | ((unsigned)f2bf(((const float*)&cvec)[j]) << 16);
            *(unsigned*)((char*)ldsV + swz(d * 64 + kp * 4)) = w;
        }
    }
    __syncthreads();
    char* kc = (char*)(Kr + (size_t)(b * NKVH + kvh) * SS * HD) + (size_t)sblk * 4096;
    char* vc = (char*)(Vt + (size_t)(b * NKVH + kvh) * HD * SS) + (size_t)sblk * 4096;
    *(short8*)(kc + tid * 16) = *(short8*)((char*)ldsK + tid * 16);
    *(short8*)(vc + tid * 16) = *(short8*)((char*)ldsV + tid * 16);
}

// ---- main v9: 64-query blocks. 8 waves = 4 GQA heads x 2 q-subblocks of one
// kvh share one staged K/V stream (staging per query HALVED vs v8). Window
// chunk count is always even -> clean pair loop, no phantom staging. Per-wave
// compute machinery (sigma in-lane P, masks, epilogue) identical to R8.
__global__ __launch_bounds__(512, 4) void attn_mfma(const float* __restrict__ Q,
                                                    const ushort* __restrict__ Kr,
                                                    const ushort* __restrict__ Vt,
                                                    float* __restrict__ O) {
    __shared__ __align__(16) ushort ldsK[2][2][2048];   // [buf][slot][chunk image]
    __shared__ __align__(16) ushort ldsV[2][2][2048];
    const int tid = threadIdx.x;
    const int wv = tid >> 6, lane = tid & 63;
    const int lo16 = lane & 15, quad = lane >> 4;
    // bijective XCD swizzle: 512 wg = 8 XCD * 64 contiguous
    const int bidx  = (blockIdx.x & 7) * 64 + (blockIdx.x >> 3);
    const int qpair = bidx & 31;
    const int kvh   = (bidx >> 5) & 7;
    const int b     = bidx >> 8;
    const int h     = kvh * 4 + (wv & 3);
    const int q0    = qpair * 64 + (wv >> 2) * 32;   // this wave's 32-query base

    float invf[8];
#pragma unroll
    for (int j = 0; j < 8; ++j)
        invf[j] = __powf(10000.f, -(float)(quad * 8 + j) * (1.f / 32.f));

    // Q load + RoPE + scale -> MFMA B-operand-shaped regs
    short8 aq[2][2];
#pragma unroll
    for (int t = 0; t < 2; ++t) {
        int qi = q0 + t * 16 + lo16;
        const float* qrow = Q + (size_t)(b * SS + qi) * (NH * HD) + h * HD;
        float lo[8], hi[8];
        *(float4*)(lo)     = *(const float4*)(qrow + quad * 8);
        *(float4*)(lo + 4) = *(const float4*)(qrow + quad * 8 + 4);
        *(float4*)(hi)     = *(const float4*)(qrow + 32 + quad * 8);
        *(float4*)(hi + 4) = *(const float4*)(qrow + 32 + quad * 8 + 4);
#pragma unroll
        for (int j = 0; j < 8; ++j) {
            float sn, cs;
            __sincosf((float)qi * invf[j], &sn, &cs);
            aq[t][0][j] = (short)f2bf((lo[j] * cs - hi[j] * sn) * 0.125f);
            aq[t][1][j] = (short)f2bf((hi[j] * cs + lo[j] * sn) * 0.125f);
        }
    }

    const char* kbase = (const char*)(Kr + (size_t)(b * NKVH + kvh) * SS * HD);
    const char* vbase = (const char*)(Vt + (size_t)(b * NKVH + kvh) * HD * SS);

    f32x4 acc[2][4];
#pragma unroll
    for (int t = 0; t < 2; ++t)
#pragma unroll
        for (int i = 0; i < 4; ++i) acc[t][i] = (f32x4){0.f, 0.f, 0.f, 0.f};
    float psum[2] = {0.f, 0.f};

    int klo = qpair * 64 - WIN; if (klo < 0) klo = 0;   // BLOCK window start
    const int c0     = klo >> 5;
    const int cnt    = 2 * qpair + 2 - c0;   // chunks in block window (always even)
    const int npairs = cnt >> 1;

    // stage one 64-key pair (4 images of 4KB): 8 waves x half-image each,
    // 2 stage16 (2KB) per wave.
    auto stagepair = [&](int pidx, int buf) {
        const int ca = c0 + 2 * pidx, cb = ca + 1;      // always in-range
        const int im   = wv >> 1;
        const int hoff = (wv & 1) * 2048;
        const char* src = (im == 0) ? kbase + (size_t)ca * 4096
                        : (im == 1) ? vbase + (size_t)ca * 4096
                        : (im == 2) ? kbase + (size_t)cb * 4096
                        :             vbase + (size_t)cb * 4096;
        char* dst = (im == 0) ? (char*)&ldsK[buf][0][0]
                  : (im == 1) ? (char*)&ldsV[buf][0][0]
                  : (im == 2) ? (char*)&ldsK[buf][1][0]
                  :             (char*)&ldsV[buf][1][0];
        stage16(src + hoff + lane * 16,        dst + hoff);
        stage16(src + hoff + 1024 + lane * 16, dst + hoff + 1024);
    };

    // per-chunk compute; P->PV hand-off pure in-register (sigma V layout)
    auto compute = [&](int kb, const char* kl, const char* vl) {
        short8 k0 = *(const short8*)(kl + swz(lo16 * 128 + quad * 16));
        short8 k1 = *(const short8*)(kl + swz(lo16 * 128 + 64 + quad * 16));
        short8 k2 = *(const short8*)(kl + swz((lo16 + 16) * 128 + quad * 16));
        short8 k3 = *(const short8*)(kl + swz((lo16 + 16) * 128 + 64 + quad * 16));

        const f32x4 z = {0.f, 0.f, 0.f, 0.f};
        __builtin_amdgcn_s_setprio(1);
        f32x4 s00 = __builtin_amdgcn_mfma_f32_16x16x32_bf16(k0, aq[0][0], z,   0, 0, 0);
        s00       = __builtin_amdgcn_mfma_f32_16x16x32_bf16(k1, aq[0][1], s00, 0, 0, 0);
        f32x4 s01 = __builtin_amdgcn_mfma_f32_16x16x32_bf16(k2, aq[0][0], z,   0, 0, 0);
        s01       = __builtin_amdgcn_mfma_f32_16x16x32_bf16(k3, aq[0][1], s01, 0, 0, 0);
        f32x4 s10 = __builtin_amdgcn_mfma_f32_16x16x32_bf16(k0, aq[1][0], z,   0, 0, 0);
        s10       = __builtin_amdgcn_mfma_f32_16x16x32_bf16(k1, aq[1][1], s10, 0, 0, 0);
        f32x4 s11 = __builtin_amdgcn_mfma_f32_16x16x32_bf16(k2, aq[1][0], z,   0, 0, 0);
        s11       = __builtin_amdgcn_mfma_f32_16x16x32_bf16(k3, aq[1][1], s11, 0, 0, 0);
        __builtin_amdgcn_s_setprio(0);

        short8 ap[2];
#pragma unroll
        for (int t = 0; t < 2; ++t) {
            const f32x4 sa = t ? s10 : s00;
            const f32x4 sb = t ? s11 : s01;
            const int qtmin = q0 + t * 16;
            const int myq   = qtmin + lo16;
            float p[8];
            if ((kb + 31 > qtmin) || (kb < qtmin + 15 - WIN)) {   // boundary: mask
#pragma unroll
                for (int r = 0; r < 4; ++r) {
                    int key0 = kb + quad * 4 + r;
                    int key1 = key0 + 16;
                    p[r]     = (key0 <= myq && key0 >= myq - WIN) ? __expf(sa[r]) : 0.f;
                    p[4 + r] = (key1 <= myq && key1 >= myq - WIN) ? __expf(sb[r]) : 0.f;
                }
            } else {
#pragma unroll
                for (int r = 0; r < 4; ++r) { p[r] = __expf(sa[r]); p[4 + r] = __expf(sb[r]); }
            }
            psum[t] += ((p[0] + p[1]) + (p[2] + p[3])) + ((p[4] + p[5]) + (p[6] + p[7]));

            union { int i[4]; short8 s; } u;
            u.i[0] = cvtpk_bf16(p[0], p[1]);
            u.i[1] = cvtpk_bf16(p[2], p[3]);
            u.i[2] = cvtpk_bf16(p[4], p[5]);
            u.i[3] = cvtpk_bf16(p[6], p[7]);
            ap[t] = u.s;
        }

        short8 vf[4];
#pragma unroll
        for (int i = 0; i < 4; ++i)
            vf[i] = *(const short8*)(vl + swz((i * 16 + lo16) * 64 + quad * 16));

        __builtin_amdgcn_s_setprio(1);
#pragma unroll
        for (int i = 0; i < 4; ++i)
            acc[0][i] = __builtin_amdgcn_mfma_f32_16x16x32_bf16(ap[0], vf[i], acc[0][i], 0, 0, 0);
#pragma unroll
        for (int i = 0; i < 4; ++i)
            acc[1][i] = __builtin_amdgcn_mfma_f32_16x16x32_bf16(ap[1], vf[i], acc[1][i], 0, 0, 0);
        __builtin_amdgcn_s_setprio(0);
    };

    // prologue: stage pair 0 into buf 0 (2 vm ops per wave)
    stagepair(0, 0);

    int nb = 0;
    for (int p = 0; p < npairs; ++p, nb ^= 1) {
        if (p + 1 < npairs) {
            stagepair(p + 1, nb ^ 1);                     // 2 new vm ops per wave
            asm volatile("s_waitcnt vmcnt(2)" ::: "memory");  // wait pair p only
        } else {
            asm volatile("s_waitcnt vmcnt(0)" ::: "memory");  // last pair: drain
        }
        __builtin_amdgcn_s_barrier();                     // raw barrier, no drain
        __builtin_amdgcn_sched_barrier(0);                // no ds_read hoisting
        compute(klo + 2 * p * 32,       (const char*)&ldsK[nb][0][0], (const char*)&ldsV[nb][0][0]);
        compute(klo + (2 * p + 1) * 32, (const char*)&ldsK[nb][1][0], (const char*)&ldsV[nb][1][0]);
        __builtin_amdgcn_sched_barrier(0);
        __builtin_amdgcn_s_barrier();                     // reads done before overwrite
    }

#pragma unroll
    for (int t = 0; t < 2; ++t) {
        float ps = psum[t];
        ps += __shfl_xor(ps, 16, 64);
        ps += __shfl_xor(ps, 32, 64);        // all lanes: total for query lo16
#pragma unroll
        for (int r = 0; r < 4; ++r) {
            float invr = 1.f / __shfl(ps, quad * 4 + r, 16);
            int qr = q0 + t * 16 + quad * 4 + r;
            size_t orow = ((size_t)(b * SS + qr) * NH + h) * HD;
            O[orow + 0 * 16 + lo16] = acc[t][0][r] * invr;
            O[orow + 1 * 16 + lo16] = acc[t][1][r] * invr;
            O[orow + 2 * 16 + lo16] = acc[t][2][r] * invr;
            O[orow + 3 * 16 + lo16] = acc[t][3][r] * invr;
        }
    }
}

// ---------- fallback (no workspace): round-1 scalar kernel ----------
__device__ __forceinline__ float wave_sum(float x) {
#pragma unroll
    for (int off = 32; off > 0; off >>= 1) x += __shfl_xor(x, off, 64);
    return x;
}

__global__ __launch_bounds__(256) void attn_scalar(const float* __restrict__ Q,
                                                   const float* __restrict__ K,
                                                   const float* __restrict__ V,
                                                   float* __restrict__ O) {
    int wave = blockIdx.x * 4 + (threadIdx.x >> 6);
    int lane = threadIdx.x & 63;
    int q  = wave % SS;
    int bh = wave / SS;
    int h  = bh % NH;
    int b  = bh / NH;
    int kvh = h >> 2;

    float inv = __powf(10000.f, -(float)(lane & 31) * (1.f / 32.f));
    float sn, cs;
    __sincosf((float)q * inv, &sn, &cs);

    float qv = Q[(size_t)(b * SS + q) * (NH * HD) + h * HD + lane];
    float qpart = __shfl(qv, lane ^ 32, 64);
    float qrot = (qv * cs + ((lane < 32) ? -qpart : qpart) * sn) * 0.125f;

    const float* vbase = V + (size_t)b * SS * (NKVH * HD) + kvh * HD;
    float m = -1e30f, l = 0.f, acc = 0.f;
    int k0 = q - WIN; if (k0 < 0) k0 = 0;
    for (int k = k0; k <= q; ++k) {
        float kraw = K[(size_t)(b * SS + k) * (NKVH * HD) + kvh * HD + lane];
        float kpart = __shfl(kraw, lane ^ 32, 64);
        float ksn, kcs;
        __sincosf((float)k * inv, &ksn, &kcs);
        float kv = kraw * kcs + ((lane < 32) ? -kpart : kpart) * ksn;
        float vv = vbase[(size_t)k * (NKVH * HD) + lane];
        float score = wave_sum(qrot * kv);
        float mnew  = fmaxf(m, score);
        float alpha = __expf(m - mnew);
        float p     = __expf(score - mnew);
        l   = l * alpha + p;
        acc = acc * alpha + p * vv;
        m   = mnew;
    }
    O[(((size_t)(b * SS + q) * NH) + h) * HD + lane] = acc / l;
}

extern "C" void kernel_launch(void* const* d_in, const int* in_sizes, int n_in,
                              void* d_out, int out_size, void* d_ws, size_t ws_size,
                              hipStream_t stream) {
    const float* Q = (const float*)d_in[0];
    const float* K = (const float*)d_in[1];
    const float* V = (const float*)d_in[2];
    float* O = (float*)d_out;

    size_t kv_elems = (size_t)BB * NKVH * SS * HD;   // 2M elements
    size_t need = 2 * kv_elems * sizeof(ushort);     // 8 MB

    if (ws_size >= need) {
        ushort* Kr = (ushort*)d_ws;
        ushort* Vt = Kr + kv_elems;
        prep_kv<<<BB * NKVH * (SS / 32), 256, 0, stream>>>(K, V, Kr, Vt);
        attn_mfma<<<BB * NKVH * (SS / 64), 512, 0, stream>>>(Q, Kr, Vt, O);
    } else {
        attn_scalar<<<(BB * NH * SS) / 4, 256, 0, stream>>>(Q, K, V, O);
    }
}

// Round 10
// 113.167 us; speedup vs baseline: 1.0164x; 1.0164x over previous
//
#include <hip/hip_runtime.h>
#include <math.h>

#define NH   32
#define NKVH 8
#define HD   64
#define WIN  256
#define BB   2
#define SS   2048

typedef short short8 __attribute__((ext_vector_type(8)));
typedef float f32x4  __attribute__((ext_vector_type(4)));

__device__ __forceinline__ ushort f2bf(float x) {
    union { float f; unsigned u; } v; v.f = x;
    unsigned u = v.u + 0x7FFF + ((v.u >> 16) & 1);   // RNE
    return (ushort)(u >> 16);
}

__device__ __forceinline__ int cvtpk_bf16(float lo, float hi) {
    int r;
    asm("v_cvt_pk_bf16_f32 %0, %1, %2" : "=v"(r) : "v"(lo), "v"(hi));
    return r;
}

// XOR-swizzle within a 4KB chunk (bits 4-6 ^= bits 7-9). Applied at prep-store
// AND lds-read; global_load_lds stages linearly so LDS holds the same image.
__device__ __forceinline__ int swz(int L) { return L ^ (((L >> 7) & 7) << 4); }

__device__ __forceinline__ void stage16(const void* g, void* l) {
    __builtin_amdgcn_global_load_lds(
        (const __attribute__((address_space(1))) unsigned int*)g,
        (__attribute__((address_space(3))) unsigned int*)l, 16, 0, 0);
}

// ---- fused pre-pass (unchanged from R8): swizzled 4KB chunk images via LDS,
// coalesced copy-out. Kr chunk: [key%32][d] bf16 rows of 128B, XOR-swizzled.
// Vt chunk: [d][slot] bf16 rows of 64B, XOR-swizzled, slot holds key
// sigma(slot) = (slot>>3)*4 + (slot&3) + ((slot>>2)&1)*16  (QK^T C-layout ==
// PV A-frag layout => no cross-lane exchange in the main kernel).
__global__ __launch_bounds__(256) void prep_kv(const float* __restrict__ K,
                                               const float* __restrict__ V,
                                               ushort* __restrict__ Kr,
                                               ushort* __restrict__ Vt) {
    __shared__ __align__(16) ushort ldsK[2048];
    __shared__ __align__(16) ushort ldsV[2048];
    const int bidx = blockIdx.x;                // (b, kvh, sblk): 2*8*64
    const int sblk = bidx & 63;
    const int s0   = sblk * 32;
    const int kvh  = (bidx >> 6) & 7;
    const int b    = bidx >> 9;
    const int tid  = threadIdx.x;

    {
        const int key = tid >> 3, dg = tid & 7;
        const int s   = s0 + key;
        const float* krow = K + (size_t)(b * SS + s) * (NKVH * HD) + kvh * HD + dg * 8;
        float x[8];
        *(float4*)(x)     = *(const float4*)(krow);
        *(float4*)(x + 4) = *(const float4*)(krow + 4);
        float inv = __powf(10000.f, -(float)((dg & 3) * 8) * (1.f / 32.f));
        const float ratio = 0.74989420933f;      // 10000^(-1/32)
        ushort out[8];
#pragma unroll
        for (int j = 0; j < 8; ++j) {
            float partner = __shfl(x[j], (tid & 63) ^ 4, 64);   // d ^ 32 holder
            float sn, cs;
            __sincosf((float)s * inv, &sn, &cs);
            out[j] = f2bf(x[j] * cs + ((dg < 4) ? -partner : partner) * sn);
            inv *= ratio;
        }
        *(short8*)((char*)ldsK + swz(key * 128 + dg * 16)) = *(short8*)out;
    }
    {
        const int kp = tid & 15, dq = tid >> 4;
        const int c  = 2 * kp;
        const int kf = ((c >> 3) * 4) + (c & 3) + (((c >> 2) & 1) * 16);
        const float* v0 = V + (size_t)(b * SS + s0 + kf) * (NKVH * HD) + kvh * HD + dq * 4;
        float4 a = *(const float4*)v0;
        float4 cvec = *(const float4*)(v0 + NKVH * HD);   // key kf+1
#pragma unroll
        for (int j = 0; j < 4; ++j) {
            int d = dq * 4 + j;
            unsigned w = (unsigned)f2bf(((const float*)&a)[j])
                       | ((unsigned)f2bf(((const float*)&cvec)[j]) << 16);
            *(unsigned*)((char*)ldsV + swz(d * 64 + kp * 4)) = w;
        }
    }
    __syncthreads();
    char* kc = (char*)(Kr + (size_t)(b * NKVH + kvh) * SS * HD) + (size_t)sblk * 4096;
    char* vc = (char*)(Vt + (size_t)(b * NKVH + kvh) * HD * SS) + (size_t)sblk * 4096;
    *(short8*)(kc + tid * 16) = *(short8*)((char*)ldsK + tid * 16);
    *(short8*)(vc + tid * 16) = *(short8*)((char*)ldsV + tid * 16);
}

// ---- main v10: R8 structure + 5-slot ring / 3-deep prefetch (m201 depth).
// Block = 4 waves = 4 GQA heads of one kvh. Iteration i: stage chunk i+3
// (phantom-clamped), s_waitcnt vmcnt(6) (own chunk-i ops retired, 3 chunks
// in flight), ONE s_barrier, compute chunk i. Reuse distance 5 > depth+1
// makes the post-compute barrier unnecessary (slot (i+3)%5 == (i-2)%5,
// whose readers finished before the barrier the staging wave has crossed).
__global__ __launch_bounds__(256, 4) void attn_mfma(const float* __restrict__ Q,
                                                    const ushort* __restrict__ Kr,
                                                    const ushort* __restrict__ Vt,
                                                    float* __restrict__ O) {
    __shared__ __align__(16) ushort ldsK[5][2048];   // 5-slot ring of chunk images
    __shared__ __align__(16) ushort ldsV[5][2048];   // total 40 KB = 4 blocks/CU
    const int wv = threadIdx.x >> 6, lane = threadIdx.x & 63;
    const int lo16 = lane & 15, quad = lane >> 4;
    // bijective XCD swizzle: 1024 wg = 8 XCD * 128 contiguous
    const int bidx = (blockIdx.x & 7) * 128 + (blockIdx.x >> 3);
    const int qblk = bidx & 63;
    const int kvh  = (bidx >> 6) & 7;
    const int b    = bidx >> 9;
    const int h    = kvh * 4 + wv;
    const int q0   = qblk * 32;

    float invf[8];
#pragma unroll
    for (int j = 0; j < 8; ++j)
        invf[j] = __powf(10000.f, -(float)(quad * 8 + j) * (1.f / 32.f));

    // Q load + RoPE + scale -> MFMA B-operand-shaped regs
    short8 aq[2][2];
#pragma unroll
    for (int t = 0; t < 2; ++t) {
        int qi = q0 + t * 16 + lo16;
        const float* qrow = Q + (size_t)(b * SS + qi) * (NH * HD) + h * HD;
        float lo[8], hi[8];
        *(float4*)(lo)     = *(const float4*)(qrow + quad * 8);
        *(float4*)(lo + 4) = *(const float4*)(qrow + quad * 8 + 4);
        *(float4*)(hi)     = *(const float4*)(qrow + 32 + quad * 8);
        *(float4*)(hi + 4) = *(const float4*)(qrow + 32 + quad * 8 + 4);
#pragma unroll
        for (int j = 0; j < 8; ++j) {
            float sn, cs;
            __sincosf((float)qi * invf[j], &sn, &cs);
            aq[t][0][j] = (short)f2bf((lo[j] * cs - hi[j] * sn) * 0.125f);
            aq[t][1][j] = (short)f2bf((hi[j] * cs + lo[j] * sn) * 0.125f);
        }
    }

    const char* kbase = (const char*)(Kr + (size_t)(b * NKVH + kvh) * SS * HD);
    const char* vbase = (const char*)(Vt + (size_t)(b * NKVH + kvh) * HD * SS);

    f32x4 acc[2][4];
#pragma unroll
    for (int t = 0; t < 2; ++t)
#pragma unroll
        for (int i = 0; i < 4; ++i) acc[t][i] = (f32x4){0.f, 0.f, 0.f, 0.f};
    float psum[2] = {0.f, 0.f};

    int klo = q0 - WIN; if (klo < 0) klo = 0;
    const int c0  = klo >> 5;
    const int cnt = (q0 >> 5) - c0 + 1;      // chunks in window (1..9)
    const int clast = c0 + cnt - 1;

    // stage one 8KB chunk (K image + V image) into ring slot: 2 vm ops/wave.
    auto stagechunk = [&](int cidx, int slot) {
        if (cidx > clast) cidx = clast;      // phantom: keeps vmcnt math uniform;
                                             // target slot is never read again.
        stage16(kbase + (size_t)cidx * 4096 + wv * 1024 + lane * 16,
                (char*)&ldsK[slot][0] + wv * 1024);
        stage16(vbase + (size_t)cidx * 4096 + wv * 1024 + lane * 16,
                (char*)&ldsV[slot][0] + wv * 1024);
    };

    // per-chunk compute; P->PV hand-off pure in-register (sigma V layout)
    auto compute = [&](int kb, const char* kl, const char* vl) {
        short8 k0 = *(const short8*)(kl + swz(lo16 * 128 + quad * 16));
        short8 k1 = *(const short8*)(kl + swz(lo16 * 128 + 64 + quad * 16));
        short8 k2 = *(const short8*)(kl + swz((lo16 + 16) * 128 + quad * 16));
        short8 k3 = *(const short8*)(kl + swz((lo16 + 16) * 128 + 64 + quad * 16));

        const f32x4 z = {0.f, 0.f, 0.f, 0.f};
        __builtin_amdgcn_s_setprio(1);
        f32x4 s00 = __builtin_amdgcn_mfma_f32_16x16x32_bf16(k0, aq[0][0], z,   0, 0, 0);
        s00       = __builtin_amdgcn_mfma_f32_16x16x32_bf16(k1, aq[0][1], s00, 0, 0, 0);
        f32x4 s01 = __builtin_amdgcn_mfma_f32_16x16x32_bf16(k2, aq[0][0], z,   0, 0, 0);
        s01       = __builtin_amdgcn_mfma_f32_16x16x32_bf16(k3, aq[0][1], s01, 0, 0, 0);
        f32x4 s10 = __builtin_amdgcn_mfma_f32_16x16x32_bf16(k0, aq[1][0], z,   0, 0, 0);
        s10       = __builtin_amdgcn_mfma_f32_16x16x32_bf16(k1, aq[1][1], s10, 0, 0, 0);
        f32x4 s11 = __builtin_amdgcn_mfma_f32_16x16x32_bf16(k2, aq[1][0], z,   0, 0, 0);
        s11       = __builtin_amdgcn_mfma_f32_16x16x32_bf16(k3, aq[1][1], s11, 0, 0, 0);
        __builtin_amdgcn_s_setprio(0);

        short8 ap[2];
#pragma unroll
        for (int t = 0; t < 2; ++t) {
            const f32x4 sa = t ? s10 : s00;
            const f32x4 sb = t ? s11 : s01;
            const int qtmin = q0 + t * 16;
            const int myq   = qtmin + lo16;
            float p[8];
            if ((kb + 31 > qtmin) || (kb < qtmin + 15 - WIN)) {   // boundary: mask
#pragma unroll
                for (int r = 0; r < 4; ++r) {
                    int key0 = kb + quad * 4 + r;
                    int key1 = key0 + 16;
                    p[r]     = (key0 <= myq && key0 >= myq - WIN) ? __expf(sa[r]) : 0.f;
                    p[4 + r] = (key1 <= myq && key1 >= myq - WIN) ? __expf(sb[r]) : 0.f;
                }
            } else {
#pragma unroll
                for (int r = 0; r < 4; ++r) { p[r] = __expf(sa[r]); p[4 + r] = __expf(sb[r]); }
            }
            psum[t] += ((p[0] + p[1]) + (p[2] + p[3])) + ((p[4] + p[5]) + (p[6] + p[7]));

            // sigma-permuted V: lane's own keys {4q+r, 16+4q+r} ARE its A-frag
            // slots {8q..8q+7}; pack to bf16 pairs in-register, done.
            union { int i[4]; short8 s; } u;
            u.i[0] = cvtpk_bf16(p[0], p[1]);
            u.i[1] = cvtpk_bf16(p[2], p[3]);
            u.i[2] = cvtpk_bf16(p[4], p[5]);
            u.i[3] = cvtpk_bf16(p[6], p[7]);
            ap[t] = u.s;
        }

        short8 vf[4];
#pragma unroll
        for (int i = 0; i < 4; ++i)
            vf[i] = *(const short8*)(vl + swz((i * 16 + lo16) * 64 + quad * 16));

        __builtin_amdgcn_s_setprio(1);
#pragma unroll
        for (int i = 0; i < 4; ++i)
            acc[0][i] = __builtin_amdgcn_mfma_f32_16x16x32_bf16(ap[0], vf[i], acc[0][i], 0, 0, 0);
#pragma unroll
        for (int i = 0; i < 4; ++i)
            acc[1][i] = __builtin_amdgcn_mfma_f32_16x16x32_bf16(ap[1], vf[i], acc[1][i], 0, 0, 0);
        __builtin_amdgcn_s_setprio(0);
    };

    // prologue: fill the pipeline 3 deep (slots 0..2; 6 vm ops per wave)
    stagechunk(c0,     0);
    stagechunk(c0 + 1, 1);
    stagechunk(c0 + 2, 2);

    for (int i = 0; i < cnt; ++i) {
        stagechunk(c0 + i + 3, (i + 3) % 5);              // keep 3 in flight
        asm volatile("s_waitcnt vmcnt(6)" ::: "memory");  // own chunk-i ops retired
        __builtin_amdgcn_s_barrier();                     // all waves' portions in LDS
        __builtin_amdgcn_sched_barrier(0);                // no ds_read hoisting (rule #18)
        compute(klo + i * 32, (const char*)&ldsK[i % 5][0], (const char*)&ldsV[i % 5][0]);
    }

#pragma unroll
    for (int t = 0; t < 2; ++t) {
        float ps = psum[t];
        ps += __shfl_xor(ps, 16, 64);
        ps += __shfl_xor(ps, 32, 64);        // all lanes: total for query lo16
#pragma unroll
        for (int r = 0; r < 4; ++r) {
            float invr = 1.f / __shfl(ps, quad * 4 + r, 16);
            int qr = q0 + t * 16 + quad * 4 + r;
            size_t orow = ((size_t)(b * SS + qr) * NH + h) * HD;
            O[orow + 0 * 16 + lo16] = acc[t][0][r] * invr;
            O[orow + 1 * 16 + lo16] = acc[t][1][r] * invr;
            O[orow + 2 * 16 + lo16] = acc[t][2][r] * invr;
            O[orow + 3 * 16 + lo16] = acc[t][3][r] * invr;
        }
    }
}

// ---------- fallback (no workspace): round-1 scalar kernel ----------
__device__ __forceinline__ float wave_sum(float x) {
#pragma unroll
    for (int off = 32; off > 0; off >>= 1) x += __shfl_xor(x, off, 64);
    return x;
}

__global__ __launch_bounds__(256) void attn_scalar(const float* __restrict__ Q,
                                                   const float* __restrict__ K,
                                                   const float* __restrict__ V,
                                                   float* __restrict__ O) {
    int wave = blockIdx.x * 4 + (threadIdx.x >> 6);
    int lane = threadIdx.x & 63;
    int q  = wave % SS;
    int bh = wave / SS;
    int h  = bh % NH;
    int b  = bh / NH;
    int kvh = h >> 2;

    float inv = __powf(10000.f, -(float)(lane & 31) * (1.f / 32.f));
    float sn, cs;
    __sincosf((float)q * inv, &sn, &cs);

    float qv = Q[(size_t)(b * SS + q) * (NH * HD) + h * HD + lane];
    float qpart = __shfl(qv, lane ^ 32, 64);
    float qrot = (qv * cs + ((lane < 32) ? -qpart : qpart) * sn) * 0.125f;

    const float* vbase = V + (size_t)b * SS * (NKVH * HD) + kvh * HD;
    float m = -1e30f, l = 0.f, acc = 0.f;
    int k0 = q - WIN; if (k0 < 0) k0 = 0;
    for (int k = k0; k <= q; ++k) {
        float kraw = K[(size_t)(b * SS + k) * (NKVH * HD) + kvh * HD + lane];
        float kpart = __shfl(kraw, lane ^ 32, 64);
        float ksn, kcs;
        __sincosf((float)k * inv, &ksn, &kcs);
        float kv = kraw * kcs + ((lane < 32) ? -kpart : kpart) * ksn;
        float vv = vbase[(size_t)k * (NKVH * HD) + lane];
        float score = wave_sum(qrot * kv);
        float mnew  = fmaxf(m, score);
        float alpha = __expf(m - mnew);
        float p     = __expf(score - mnew);
        l   = l * alpha + p;
        acc = acc * alpha + p * vv;
        m   = mnew;
    }
    O[(((size_t)(b * SS + q) * NH) + h) * HD + lane] = acc / l;
}

extern "C" void kernel_launch(void* const* d_in, const int* in_sizes, int n_in,
                              void* d_out, int out_size, void* d_ws, size_t ws_size,
                              hipStream_t stream) {
    const float* Q = (const float*)d_in[0];
    const float* K = (const float*)d_in[1];
    const float* V = (const float*)d_in[2];
    float* O = (float*)d_out;

    size_t kv_elems = (size_t)BB * NKVH * SS * HD;   // 2M elements
    size_t need = 2 * kv_elems * sizeof(ushort);     // 8 MB

    if (ws_size >= need) {
        ushort* Kr = (ushort*)d_ws;
        ushort* Vt = Kr + kv_elems;
        prep_kv<<<BB * NKVH * (SS / 32), 256, 0, stream>>>(K, V, Kr, Vt);
        attn_mfma<<<BB * NKVH * (SS / 32), 256, 0, stream>>>(Q, Kr, Vt, O);
    } else {
        attn_scalar<<<(BB * NH * SS) / 4, 256, 0, stream>>>(Q, K, V, O);
    }
}